// Round 1
// baseline (189.865 us; speedup 1.0000x reference)
//
#include <hip/hip_runtime.h>

// Fused single-kernel GEMV chain for the DCE'd MHA (kv_len==1 => softmax==1):
//   v    = v_w  @ text + v_b              (2048 x 4096, 32 MB)
//   ctx  = wv   @ v    + bv               (2048 x 2048, 16 MB)  wv = in_w rows 4096..6143
//   attn = mo_w @ ctx  + mo_b             (2048 x 2048, 16 MB)
//   out  = visual + o_w @ attn + o_b      (4096 x 2048, 32 MB)
//
// Round-3 theory: 4-kernel version pays ~3 us per kernel boundary (drain + launch)
// on top of the ~15 us / 96 MB streaming floor. Only the 8 KB x-vector is
// dependent between stages; weights depend on NOTHING. So: one persistent kernel,
// weights for stage s+1 loaded into REGISTERS before the stage-s barrier, relaxed
// spin on a release flag while those loads fly, then only the tiny x-load sits on
// the critical path. HBM never idles across stage transitions.
//
// Safety vs round-2's cooperative grid.sync() disaster (466 us):
//  - hand-rolled 2-level tree barrier (32 leaf counters + root + release flag)
//  - spin uses RELAXED agent-scope loads + s_sleep (no buffer_inv per poll);
//    exactly one __threadfence (release) before arrive and one (acquire) after
//    release is observed -> correct across non-coherent per-XCD L2s (wbl2/inv).
//  - 1024 blocks x 256 thr, __launch_bounds__(256,4) caps VGPR at 128 ->
//    4 blocks/CU co-resident is a register-file certainty (4x128=512/SIMD);
//    grid = 256 CUs x 4 -> all blocks resident, no deadlock.
//  - bounded spin: bails out (wrong answer, visible fail) instead of hanging.
//  - flags live in d_ws (poisoned every iter) -> 768 B hipMemsetAsync first.

#define ED 2048
#define VD 4096
#define NB 1024
#define NT 256

__device__ __forceinline__ float wave_red(float v) {
#pragma unroll
    for (int off = 32; off > 0; off >>= 1) v += __shfl_down(v, off, 64);
    return v;
}

__device__ __forceinline__ void barrier_arrive(unsigned* base, int b) {
    if (threadIdx.x == 0) {
        __threadfence();   // release: push this block's stores past L2 (wbl2 sc1)
        if (atomicAdd(base + (b >> 5), 1u) == 31u)       // 32 blocks per leaf
            if (atomicAdd(base + 32, 1u) == 31u)         // 32 leaves
                __hip_atomic_store(base + 33, 1u, __ATOMIC_RELAXED,
                                   __HIP_MEMORY_SCOPE_AGENT);
    }
}

__device__ __forceinline__ void barrier_wait(unsigned* base) {
    if (threadIdx.x == 0) {
        int spins = 0;
        while (__hip_atomic_load(base + 33, __ATOMIC_RELAXED,
                                 __HIP_MEMORY_SCOPE_AGENT) == 0u) {
            __builtin_amdgcn_s_sleep(1);
            if (++spins > (1 << 20)) break;   // bail out rather than hang the GPU
        }
        __threadfence();   // acquire: invalidate L1/L2 so x-reads are fresh
    }
    __syncthreads();       // releases whole block after t0's fence completed
}

__global__ __launch_bounds__(NT, 4)
void fused_chain(const float* __restrict__ visual,
                 const float* __restrict__ text,
                 const float* __restrict__ v_w,  const float* __restrict__ v_b,
                 const float* __restrict__ wv,   const float* __restrict__ bv,
                 const float* __restrict__ mo_w, const float* __restrict__ mo_b,
                 const float* __restrict__ o_w,  const float* __restrict__ o_b,
                 float* __restrict__ vvec, float* __restrict__ ctx,
                 float* __restrict__ attn, unsigned* __restrict__ flags,
                 float* __restrict__ out)
{
    const int t    = threadIdx.x;
    const int b    = blockIdx.x;
    const int lane = t & 63;
    const int wid  = t >> 6;
    __shared__ float lds[16];

    const int r2 = 2 * b;   // row pair for stages 1-3
    const int r4 = 4 * b;   // row quad for stage 4

    // ---- tiny prefetch: biases + residual (t0 only, issued up front) ----
    float bi10 = 0.f, bi11 = 0.f, bi20 = 0.f, bi21 = 0.f, bi30 = 0.f, bi31 = 0.f;
    float bo0 = 0.f, bo1 = 0.f, bo2 = 0.f, bo3 = 0.f;
    float rv0 = 0.f, rv1 = 0.f, rv2 = 0.f, rv3 = 0.f;
    if (t == 0) {
        bi10 = v_b[r2];   bi11 = v_b[r2 + 1];
        bi20 = bv[r2];    bi21 = bv[r2 + 1];
        bi30 = mo_b[r2];  bi31 = mo_b[r2 + 1];
        bo0 = o_b[r4];    bo1 = o_b[r4 + 1];  bo2 = o_b[r4 + 2];  bo3 = o_b[r4 + 3];
        rv0 = visual[r4]; rv1 = visual[r4+1]; rv2 = visual[r4+2]; rv3 = visual[r4+3];
    }

    // ---- stage-1 loads (W1: 2 rows x 4 f4, x1: 4 f4) + W2 prefetch (4 f4) ----
    const float4* w1a = (const float4*)(v_w + (size_t)r2 * VD);
    const float4* w1b = (const float4*)(v_w + (size_t)(r2 + 1) * VD);
    const float4* x1p = (const float4*)text;
    float4 w10[4], w11[4], x1[4];
#pragma unroll
    for (int j = 0; j < 4; ++j) w10[j] = w1a[t + j * NT];
#pragma unroll
    for (int j = 0; j < 4; ++j) w11[j] = w1b[t + j * NT];
#pragma unroll
    for (int j = 0; j < 4; ++j) x1[j]  = x1p[t + j * NT];

    const float4* w2a = (const float4*)(wv + (size_t)r2 * ED);
    const float4* w2b = (const float4*)(wv + (size_t)(r2 + 1) * ED);
    float4 w20[2], w21[2];
#pragma unroll
    for (int j = 0; j < 2; ++j) w20[j] = w2a[t + j * NT];
#pragma unroll
    for (int j = 0; j < 2; ++j) w21[j] = w2b[t + j * NT];

    // ---- stage 1: v = v_w @ text + v_b ----
    float a0 = 0.f, a1 = 0.f;
#pragma unroll
    for (int j = 0; j < 4; ++j) {
        a0 = fmaf(w10[j].x, x1[j].x, a0); a0 = fmaf(w10[j].y, x1[j].y, a0);
        a0 = fmaf(w10[j].z, x1[j].z, a0); a0 = fmaf(w10[j].w, x1[j].w, a0);
        a1 = fmaf(w11[j].x, x1[j].x, a1); a1 = fmaf(w11[j].y, x1[j].y, a1);
        a1 = fmaf(w11[j].z, x1[j].z, a1); a1 = fmaf(w11[j].w, x1[j].w, a1);
    }
    a0 = wave_red(a0); a1 = wave_red(a1);
    if (lane == 0) { lds[wid] = a0; lds[4 + wid] = a1; }
    __syncthreads();
    if (t == 0) {
        vvec[r2]     = lds[0] + lds[1] + lds[2] + lds[3] + bi10;
        vvec[r2 + 1] = lds[4] + lds[5] + lds[6] + lds[7] + bi11;
    }
    barrier_arrive(flags, b);

    // ---- W3 prefetch flies while stragglers finish stage 1 + we spin ----
    const float4* w3a = (const float4*)(mo_w + (size_t)r2 * ED);
    const float4* w3b = (const float4*)(mo_w + (size_t)(r2 + 1) * ED);
    float4 w30[2], w31[2];
#pragma unroll
    for (int j = 0; j < 2; ++j) w30[j] = w3a[t + j * NT];
#pragma unroll
    for (int j = 0; j < 2; ++j) w31[j] = w3b[t + j * NT];

    barrier_wait(flags);

    // ---- stage 2: ctx = wv @ v + bv (weights already in registers) ----
    const float4* xvp = (const float4*)vvec;
    float4 x2[2];
#pragma unroll
    for (int j = 0; j < 2; ++j) x2[j] = xvp[t + j * NT];
    a0 = 0.f; a1 = 0.f;
#pragma unroll
    for (int j = 0; j < 2; ++j) {
        a0 = fmaf(w20[j].x, x2[j].x, a0); a0 = fmaf(w20[j].y, x2[j].y, a0);
        a0 = fmaf(w20[j].z, x2[j].z, a0); a0 = fmaf(w20[j].w, x2[j].w, a0);
        a1 = fmaf(w21[j].x, x2[j].x, a1); a1 = fmaf(w21[j].y, x2[j].y, a1);
        a1 = fmaf(w21[j].z, x2[j].z, a1); a1 = fmaf(w21[j].w, x2[j].w, a1);
    }
    a0 = wave_red(a0); a1 = wave_red(a1);
    if (lane == 0) { lds[wid] = a0; lds[4 + wid] = a1; }
    __syncthreads();
    if (t == 0) {
        ctx[r2]     = lds[0] + lds[1] + lds[2] + lds[3] + bi20;
        ctx[r2 + 1] = lds[4] + lds[5] + lds[6] + lds[7] + bi21;
    }
    barrier_arrive(flags + 64, b);

    // ---- W4 first half (rows r4, r4+1) prefetch across barrier 2 ----
    const float4* w4a = (const float4*)(o_w + (size_t)r4 * ED);
    const float4* w4b = (const float4*)(o_w + (size_t)(r4 + 1) * ED);
    float4 w40[2], w41[2];
#pragma unroll
    for (int j = 0; j < 2; ++j) w40[j] = w4a[t + j * NT];
#pragma unroll
    for (int j = 0; j < 2; ++j) w41[j] = w4b[t + j * NT];

    barrier_wait(flags + 64);

    // ---- stage 3: attn = mo_w @ ctx + mo_b ----
    const float4* xcp = (const float4*)ctx;
    float4 x3[2];
#pragma unroll
    for (int j = 0; j < 2; ++j) x3[j] = xcp[t + j * NT];
    // Pin issue order: x3 first, THEN W4 second half -> the vmcnt wait for x3
    // (vmcnt(4)) does not trap the W4b stream; W4b overlaps S3 compute + barrier 3.
    __builtin_amdgcn_sched_barrier(0);
    const float4* w4c = (const float4*)(o_w + (size_t)(r4 + 2) * ED);
    const float4* w4d = (const float4*)(o_w + (size_t)(r4 + 3) * ED);
    float4 w42[2], w43[2];
#pragma unroll
    for (int j = 0; j < 2; ++j) w42[j] = w4c[t + j * NT];
#pragma unroll
    for (int j = 0; j < 2; ++j) w43[j] = w4d[t + j * NT];

    a0 = 0.f; a1 = 0.f;
#pragma unroll
    for (int j = 0; j < 2; ++j) {
        a0 = fmaf(w30[j].x, x3[j].x, a0); a0 = fmaf(w30[j].y, x3[j].y, a0);
        a0 = fmaf(w30[j].z, x3[j].z, a0); a0 = fmaf(w30[j].w, x3[j].w, a0);
        a1 = fmaf(w31[j].x, x3[j].x, a1); a1 = fmaf(w31[j].y, x3[j].y, a1);
        a1 = fmaf(w31[j].z, x3[j].z, a1); a1 = fmaf(w31[j].w, x3[j].w, a1);
    }
    a0 = wave_red(a0); a1 = wave_red(a1);
    if (lane == 0) { lds[wid] = a0; lds[4 + wid] = a1; }
    __syncthreads();
    if (t == 0) {
        attn[r2]     = lds[0] + lds[1] + lds[2] + lds[3] + bi30;
        attn[r2 + 1] = lds[4] + lds[5] + lds[6] + lds[7] + bi31;
    }
    barrier_arrive(flags + 128, b);
    barrier_wait(flags + 128);

    // ---- stage 4: out = visual + o_w @ attn + o_b (4 rows/block) ----
    const float4* xap = (const float4*)attn;
    float4 x4[2];
#pragma unroll
    for (int j = 0; j < 2; ++j) x4[j] = xap[t + j * NT];
    float c0 = 0.f, c1 = 0.f, c2 = 0.f, c3 = 0.f;
#pragma unroll
    for (int j = 0; j < 2; ++j) {
        c0 = fmaf(w40[j].x, x4[j].x, c0); c0 = fmaf(w40[j].y, x4[j].y, c0);
        c0 = fmaf(w40[j].z, x4[j].z, c0); c0 = fmaf(w40[j].w, x4[j].w, c0);
        c1 = fmaf(w41[j].x, x4[j].x, c1); c1 = fmaf(w41[j].y, x4[j].y, c1);
        c1 = fmaf(w41[j].z, x4[j].z, c1); c1 = fmaf(w41[j].w, x4[j].w, c1);
        c2 = fmaf(w42[j].x, x4[j].x, c2); c2 = fmaf(w42[j].y, x4[j].y, c2);
        c2 = fmaf(w42[j].z, x4[j].z, c2); c2 = fmaf(w42[j].w, x4[j].w, c2);
        c3 = fmaf(w43[j].x, x4[j].x, c3); c3 = fmaf(w43[j].y, x4[j].y, c3);
        c3 = fmaf(w43[j].z, x4[j].z, c3); c3 = fmaf(w43[j].w, x4[j].w, c3);
    }
    c0 = wave_red(c0); c1 = wave_red(c1); c2 = wave_red(c2); c3 = wave_red(c3);
    if (lane == 0) {
        lds[wid] = c0; lds[4 + wid] = c1; lds[8 + wid] = c2; lds[12 + wid] = c3;
    }
    __syncthreads();
    if (t == 0) {
        out[r4]     = lds[0]  + lds[1]  + lds[2]  + lds[3]  + bo0 + rv0;
        out[r4 + 1] = lds[4]  + lds[5]  + lds[6]  + lds[7]  + bo1 + rv1;
        out[r4 + 2] = lds[8]  + lds[9]  + lds[10] + lds[11] + bo2 + rv2;
        out[r4 + 3] = lds[12] + lds[13] + lds[14] + lds[15] + bo3 + rv3;
    }
}

extern "C" void kernel_launch(void* const* d_in, const int* in_sizes, int n_in,
                              void* d_out, int out_size, void* d_ws, size_t ws_size,
                              hipStream_t stream) {
    (void)in_sizes; (void)n_in; (void)out_size; (void)ws_size;
    const float* visual = (const float*)d_in[0];   // [4096]
    const float* text   = (const float*)d_in[1];   // [4096]
    // d_in[2..5] = q_w, q_b, k_w, k_b -> dead (softmax over single key == 1)
    const float* v_w  = (const float*)d_in[6];     // [2048, 4096]
    const float* v_b  = (const float*)d_in[7];     // [2048]
    const float* in_w = (const float*)d_in[8];     // [6144, 2048]
    const float* in_b = (const float*)d_in[9];     // [6144]
    const float* mo_w = (const float*)d_in[10];    // [2048, 2048]
    const float* mo_b = (const float*)d_in[11];    // [2048]
    const float* o_w  = (const float*)d_in[12];    // [4096, 2048]
    const float* o_b  = (const float*)d_in[13];    // [4096]
    float* out = (float*)d_out;                    // [4096]

    const float* wv = in_w + (size_t)2 * ED * ED;  // in_w rows 4096..6143
    const float* bv = in_b + 2 * ED;

    float* ws   = (float*)d_ws;
    float* vvec = ws;               // [2048]
    float* ctx  = ws + ED;          // [2048]
    float* attn = ws + 2 * ED;      // [2048]
    unsigned* flags = (unsigned*)(ws + 8192);   // 3 stages x 64 uints, 32KB offset

    // Workspace is poisoned between iterations -> barrier state must be zeroed.
    hipMemsetAsync(flags, 0, 3 * 64 * sizeof(unsigned), stream);
    fused_chain<<<NB, NT, 0, stream>>>(visual, text, v_w, v_b, wv, bv,
                                       mo_w, mo_b, o_w, o_b,
                                       vvec, ctx, attn, flags, out);
}